// Round 1
// baseline (129.477 us; speedup 1.0000x reference)
//
#include <hip/hip_runtime.h>
#include <hip/hip_bf16.h>

typedef __bf16 bf16x8 __attribute__((ext_vector_type(8)));
typedef float f32x4 __attribute__((ext_vector_type(4)));

#define N_NODES 32
#define FDIM 256
#define N_TYPES 8
#define BT_TILE 128
#define BK 64

// XOR swizzle: row stride is BK*2=128B -> 16-way bank conflict on ds_read_b128
// without it. (row&7)<<4 permutes 16B slots within each 8-row stripe; applied
// identically on write and read.
__device__ __forceinline__ unsigned swz(unsigned byte_off, unsigned row) {
    return byte_off ^ ((row & 7u) << 4);
}

// ---------------------------------------------------------------------------
// Kernel 1: per-node GEMM. Block = (bt_block, n). C[128 bt, 256 o] =
// A[128, 256 k] @ W[type(n)][o, k]^T, bf16 MFMA 16x16x32, fp32 accum.
// Epilogue adds bias[type(n)][o]; stores fp32 out1 to d_out[bt, n, o].
// ---------------------------------------------------------------------------
__global__ __launch_bounds__(256) void k1_node_gemm(
    const float* __restrict__ input, const float* __restrict__ weight,
    const float* __restrict__ bias, const int* __restrict__ ntype,
    float* __restrict__ out)
{
    __shared__ __bf16 sA[BT_TILE * BK];   // [r][k], swizzled, 16 KB
    __shared__ __bf16 sB[FDIM * BK];      // [o][k], swizzled, 32 KB

    const int tid = threadIdx.x;
    const int n = blockIdx.y;
    const int bt0 = blockIdx.x * BT_TILE;
    const int t = ntype[n];

    const float* Abase = input + (size_t)bt0 * (N_NODES * FDIM) + n * FDIM;
    const float* Wbase = weight + (size_t)t * FDIM * FDIM;

    const int wid = tid >> 6;
    const int lane = tid & 63;
    const int wm = wid >> 1;          // wave row: 0..1  (64 bt-rows each)
    const int wn = wid & 1;           // wave col: 0..1  (128 o-cols each)
    const int lr = lane & 15;
    const int lq = lane >> 4;

    f32x4 acc[4][8];
#pragma unroll
    for (int mf = 0; mf < 4; ++mf)
#pragma unroll
        for (int nf = 0; nf < 8; ++nf)
            acc[mf][nf] = f32x4{0.f, 0.f, 0.f, 0.f};

    char* sAb = (char*)sA;
    char* sBb = (char*)sB;

    const int rbase = tid >> 3;        // 0..31
    const int kk8 = (tid & 7) * 8;     // 0,8,..,56

    for (int k0 = 0; k0 < FDIM; k0 += BK) {
        __syncthreads();
        // stage A: 128 rows x 64 k (fp32 -> bf16)
#pragma unroll
        for (int p = 0; p < 4; ++p) {
            int r = rbase + p * 32;
            const float* gp = Abase + (size_t)r * (N_NODES * FDIM) + k0 + kk8;
            float4 f0 = reinterpret_cast<const float4*>(gp)[0];
            float4 f1 = reinterpret_cast<const float4*>(gp)[1];
            bf16x8 h;
            h[0] = (__bf16)f0.x; h[1] = (__bf16)f0.y;
            h[2] = (__bf16)f0.z; h[3] = (__bf16)f0.w;
            h[4] = (__bf16)f1.x; h[5] = (__bf16)f1.y;
            h[6] = (__bf16)f1.z; h[7] = (__bf16)f1.w;
            *reinterpret_cast<bf16x8*>(sAb + swz(r * (BK * 2) + kk8 * 2, r)) = h;
        }
        // stage B: 256 o-rows x 64 k (fp32 -> bf16), W kept [o][k] row-major
#pragma unroll
        for (int p = 0; p < 8; ++p) {
            int o = rbase + p * 32;
            const float* gp = Wbase + (size_t)o * FDIM + k0 + kk8;
            float4 f0 = reinterpret_cast<const float4*>(gp)[0];
            float4 f1 = reinterpret_cast<const float4*>(gp)[1];
            bf16x8 h;
            h[0] = (__bf16)f0.x; h[1] = (__bf16)f0.y;
            h[2] = (__bf16)f0.z; h[3] = (__bf16)f0.w;
            h[4] = (__bf16)f1.x; h[5] = (__bf16)f1.y;
            h[6] = (__bf16)f1.z; h[7] = (__bf16)f1.w;
            *reinterpret_cast<bf16x8*>(sBb + swz(o * (BK * 2) + kk8 * 2, o)) = h;
        }
        __syncthreads();

#pragma unroll
        for (int kk = 0; kk < BK; kk += 32) {
            const int kb = (kk + lq * 8) * 2;   // byte offset of this lane's 8 bf16
            bf16x8 af[4], bv[8];
#pragma unroll
            for (int mf = 0; mf < 4; ++mf) {
                int r = wm * 64 + mf * 16 + lr;
                af[mf] = *reinterpret_cast<const bf16x8*>(sAb + swz(r * (BK * 2) + kb, r));
            }
#pragma unroll
            for (int nf = 0; nf < 8; ++nf) {
                int o = wn * 128 + nf * 16 + lr;
                bv[nf] = *reinterpret_cast<const bf16x8*>(sBb + swz(o * (BK * 2) + kb, o));
            }
#pragma unroll
            for (int mf = 0; mf < 4; ++mf)
#pragma unroll
                for (int nf = 0; nf < 8; ++nf)
                    acc[mf][nf] = __builtin_amdgcn_mfma_f32_16x16x32_bf16(
                        af[mf], bv[nf], acc[mf][nf], 0, 0, 0);
        }
    }

    // epilogue: += bias, store fp32. D layout: row=(lane>>4)*4+j, col=lane&15.
#pragma unroll
    for (int nf = 0; nf < 8; ++nf) {
        int o = wn * 128 + nf * 16 + lr;
        float bval = bias[t * FDIM + o];
#pragma unroll
        for (int mf = 0; mf < 4; ++mf) {
#pragma unroll
            for (int j = 0; j < 4; ++j) {
                int r = wm * 64 + mf * 16 + lq * 4 + j;
                out[(size_t)(bt0 + r) * (N_NODES * FDIM) + n * FDIM + o] =
                    acc[mf][nf][j] + bval;
            }
        }
    }
}

// ---------------------------------------------------------------------------
// Kernel 2: in-place graph aggregation. out2[bt,:,o] = g @ out1[bt,:,o].
// Each thread owns one (bt, o) column: read 32 -> regs, 1024 FMA, write 32.
// Column-disjoint => in-place safe with no synchronization.
// ---------------------------------------------------------------------------
__global__ __launch_bounds__(256) void k2_graph_agg(
    float* __restrict__ out, const float* __restrict__ g)
{
    __shared__ float gs[N_NODES * N_NODES];
    const int tid = threadIdx.x;
#pragma unroll
    for (int i = tid; i < N_NODES * N_NODES; i += 256) gs[i] = g[i];
    __syncthreads();

    const int bt = blockIdx.x;       // one bt per block
    const int o = tid;               // 256 columns
    float* base = out + (size_t)bt * (N_NODES * FDIM) + o;

    float v[N_NODES];
#pragma unroll
    for (int nn = 0; nn < N_NODES; ++nn) v[nn] = base[nn * FDIM];

#pragma unroll 4
    for (int m = 0; m < N_NODES; ++m) {
        float s = 0.f;
#pragma unroll
        for (int nn = 0; nn < N_NODES; ++nn)
            s = fmaf(gs[m * N_NODES + nn], v[nn], s);
        base[m * FDIM] = s;
    }
}

extern "C" void kernel_launch(void* const* d_in, const int* in_sizes, int n_in,
                              void* d_out, int out_size, void* d_ws, size_t ws_size,
                              hipStream_t stream) {
    const float* input  = (const float*)d_in[0];
    const float* g      = (const float*)d_in[1];
    const int*   ntype  = (const int*)d_in[2];
    const float* weight = (const float*)d_in[3];
    const float* bias   = (const float*)d_in[4];
    float* out = (float*)d_out;

    const int BT = in_sizes[0] / (N_NODES * FDIM);   // 4096

    dim3 g1(BT / BT_TILE, N_NODES);
    k1_node_gemm<<<g1, 256, 0, stream>>>(input, weight, bias, ntype, out);

    k2_graph_agg<<<BT, 256, 0, stream>>>(out, g);
}

// Round 2
// 126.649 us; speedup vs baseline: 1.0223x; 1.0223x over previous
//
#include <hip/hip_runtime.h>
#include <hip/hip_bf16.h>
#include <stdint.h>

typedef __bf16 bf16x8 __attribute__((ext_vector_type(8)));
typedef float f32x4 __attribute__((ext_vector_type(4)));

#define N_NODES 32
#define FDIM 256
#define N_TYPES 8
#define BT_TILE 64
#define BK 64
#define NKCH (FDIM / BK)          // 4 K-chunks
#define WCHUNK_BYTES (FDIM * BK * 2)   // 32768 bytes per (type, chunk)

// XOR swizzle: row stride 128B -> same-bank column without it; (row&7)<<4
// spreads the 16B slots across 8 positions. Applied on write AND read.
__device__ __forceinline__ unsigned swz(unsigned byte_off, unsigned row) {
    return byte_off ^ ((row & 7u) << 4);
}

__device__ __forceinline__ void lds_dma16(void* lds, const void* g) {
    __builtin_amdgcn_global_load_lds(
        (const __attribute__((address_space(1))) unsigned int*)g,
        (__attribute__((address_space(3))) unsigned int*)lds, 16, 0, 0);
}

// ---------------------------------------------------------------------------
// k0: one-time weight fp32 -> bf16, PRE-SWIZZLED so k1 can stage with linear
// global_load_lds. Layout: wp[(t*4 + c) * 16 KB-image], image byte
// L = (o*128 + kl*2) ^ ((o&7)<<4) holds W[t][o][c*64+kl].
// ---------------------------------------------------------------------------
__global__ __launch_bounds__(256) void k0_convert_w(
    const float* __restrict__ w, __bf16* __restrict__ wp)
{
    int idx = blockIdx.x * 256 + threadIdx.x;      // [t][o][k] linear
    int o = (idx >> 8) & 255;
    int k = idx & 255;
    float v = w[idx];
    int t = idx >> 16;
    int c = k >> 6, kl = k & 63;
    unsigned L = (unsigned)(o * 128 + kl * 2) ^ ((o & 7u) << 4);
    wp[(size_t)(t * NKCH + c) * (WCHUNK_BYTES / 2) + (L >> 1)] = (__bf16)v;
}

// ---------------------------------------------------------------------------
// k1: per-node GEMM, C[64 bt x 256 o] = A[64 x 256k] @ W[t]^T.
// Double-buffered: W via global_load_lds DMA (pre-swizzled source),
// A via reg-stage (issue early) -> cvt -> swizzled ds_write (late). One
// barrier per K-chunk. 4 waves, each owns a 64x64 output quadrant.
// ---------------------------------------------------------------------------
__global__ __launch_bounds__(256, 2) void k1_node_gemm(
    const float* __restrict__ input, const __bf16* __restrict__ wp,
    const float* __restrict__ bias, const int* __restrict__ ntype,
    float* __restrict__ out)
{
    __shared__ __bf16 sA[2][BT_TILE * BK];   // 2 x 8 KB
    __shared__ __bf16 sW[2][FDIM * BK];      // 2 x 32 KB

    const int tid = threadIdx.x;
    const int n = blockIdx.y;
    const int bt0 = blockIdx.x * BT_TILE;
    const int t = ntype[n];

    const float* Abase = input + (size_t)bt0 * (N_NODES * FDIM) + n * FDIM;
    const char* Wbase = (const char*)wp + (size_t)t * NKCH * WCHUNK_BYTES;

    const int wid = tid >> 6, lane = tid & 63;
    const int lr = lane & 15, lq = lane >> 4;
    const int wn = wid;                  // wave's 64-col band

    const int ar = tid >> 2;             // A row this thread stages (0..63)
    const int akb = (tid & 3) * 32;      // byte offset within 128B bf16 row

    f32x4 acc[4][4];
#pragma unroll
    for (int mf = 0; mf < 4; ++mf)
#pragma unroll
        for (int nf = 0; nf < 4; ++nf)
            acc[mf][nf] = f32x4{0.f, 0.f, 0.f, 0.f};

    char* sAb0 = (char*)sA[0]; char* sAb1 = (char*)sA[1];
    char* sWb0 = (char*)sW[0]; char* sWb1 = (char*)sW[1];

    float4 av[4];

    // ---- prologue: stage chunk 0 into buffer 0 ----
    {
        const float* gp = Abase + (size_t)ar * (N_NODES * FDIM) + (tid & 3) * 16;
#pragma unroll
        for (int q = 0; q < 4; ++q)
            av[q] = reinterpret_cast<const float4*>(gp)[q];
#pragma unroll
        for (int j = 0; j < 8; ++j)
            lds_dma16(sWb0 + j * 4096 + tid * 16, Wbase + j * 4096 + tid * 16);
        bf16x8 h0, h1;
        h0[0]=(__bf16)av[0].x; h0[1]=(__bf16)av[0].y; h0[2]=(__bf16)av[0].z; h0[3]=(__bf16)av[0].w;
        h0[4]=(__bf16)av[1].x; h0[5]=(__bf16)av[1].y; h0[6]=(__bf16)av[1].z; h0[7]=(__bf16)av[1].w;
        h1[0]=(__bf16)av[2].x; h1[1]=(__bf16)av[2].y; h1[2]=(__bf16)av[2].z; h1[3]=(__bf16)av[2].w;
        h1[4]=(__bf16)av[3].x; h1[5]=(__bf16)av[3].y; h1[6]=(__bf16)av[3].z; h1[7]=(__bf16)av[3].w;
        *reinterpret_cast<bf16x8*>(sAb0 + swz(ar * 128 + akb,      ar)) = h0;
        *reinterpret_cast<bf16x8*>(sAb1 - (sAb1 - sAb0) + swz(ar * 128 + akb + 16, ar)) = h1; // == sAb0
    }
    __syncthreads();

    int cur = 0;
#pragma unroll
    for (int c = 0; c < NKCH; ++c) {
        char* sAcur = cur ? sAb1 : sAb0;
        char* sWcur = cur ? sWb1 : sWb0;
        char* sAnxt = cur ? sAb0 : sAb1;
        char* sWnxt = cur ? sWb0 : sWb1;

        if (c + 1 < NKCH) {
            // issue next A chunk (global -> regs) EARLY
            const float* gp = Abase + (size_t)ar * (N_NODES * FDIM)
                              + (c + 1) * BK + (tid & 3) * 16;
#pragma unroll
            for (int q = 0; q < 4; ++q)
                av[q] = reinterpret_cast<const float4*>(gp)[q];
            // issue next W chunk DMA EARLY (drains at the barrier below)
            const char* wsrc = Wbase + (size_t)(c + 1) * WCHUNK_BYTES;
#pragma unroll
            for (int j = 0; j < 8; ++j)
                lds_dma16(sWnxt + j * 4096 + tid * 16, wsrc + j * 4096 + tid * 16);
        }

        // ---- compute on current buffers ----
#pragma unroll
        for (int kk = 0; kk < BK; kk += 32) {
            const int kb = (kk + lq * 8) * 2;
            bf16x8 af[4], bf[4];
#pragma unroll
            for (int mf = 0; mf < 4; ++mf) {
                int r = mf * 16 + lr;
                af[mf] = *reinterpret_cast<const bf16x8*>(sAcur + swz(r * 128 + kb, r));
            }
#pragma unroll
            for (int nf = 0; nf < 4; ++nf) {
                int o = wn * 64 + nf * 16 + lr;
                bf[nf] = *reinterpret_cast<const bf16x8*>(sWcur + swz(o * 128 + kb, o));
            }
#pragma unroll
            for (int mf = 0; mf < 4; ++mf)
#pragma unroll
                for (int nf = 0; nf < 4; ++nf)
                    acc[mf][nf] = __builtin_amdgcn_mfma_f32_16x16x32_bf16(
                        af[mf], bf[nf], acc[mf][nf], 0, 0, 0);
        }

        if (c + 1 < NKCH) {
            // cvt + swizzled ds_write LATE (load latency hid under MFMA)
            bf16x8 h0, h1;
            h0[0]=(__bf16)av[0].x; h0[1]=(__bf16)av[0].y; h0[2]=(__bf16)av[0].z; h0[3]=(__bf16)av[0].w;
            h0[4]=(__bf16)av[1].x; h0[5]=(__bf16)av[1].y; h0[6]=(__bf16)av[1].z; h0[7]=(__bf16)av[1].w;
            h1[0]=(__bf16)av[2].x; h1[1]=(__bf16)av[2].y; h1[2]=(__bf16)av[2].z; h1[3]=(__bf16)av[2].w;
            h1[4]=(__bf16)av[3].x; h1[5]=(__bf16)av[3].y; h1[6]=(__bf16)av[3].z; h1[7]=(__bf16)av[3].w;
            *reinterpret_cast<bf16x8*>(sAnxt + swz(ar * 128 + akb,      ar)) = h0;
            *reinterpret_cast<bf16x8*>(sAnxt + swz(ar * 128 + akb + 16, ar)) = h1;
        }
        __syncthreads();
        cur ^= 1;
    }

    // ---- epilogue: += bias, store. D layout: row=(lane>>4)*4+j, col=lane&15.
#pragma unroll
    for (int nf = 0; nf < 4; ++nf) {
        int o = wn * 64 + nf * 16 + lr;
        float bval = bias[t * FDIM + o];
#pragma unroll
        for (int mf = 0; mf < 4; ++mf) {
#pragma unroll
            for (int j = 0; j < 4; ++j) {
                int r = bt0 + mf * 16 + lq * 4 + j;
                out[(size_t)r * (N_NODES * FDIM) + n * FDIM + o] =
                    acc[mf][nf][j] + bval;
            }
        }
    }
}

// ---------------------------------------------------------------------------
// k2: in-place graph aggregation. out2[bt,:,o] = g @ out1[bt,:,o].
// Column-disjoint per thread => in-place safe.
// ---------------------------------------------------------------------------
__global__ __launch_bounds__(256) void k2_graph_agg(
    float* __restrict__ out, const float* __restrict__ g)
{
    __shared__ float gs[N_NODES * N_NODES];
    const int tid = threadIdx.x;
#pragma unroll
    for (int i = tid; i < N_NODES * N_NODES; i += 256) gs[i] = g[i];
    __syncthreads();

    const int bt = blockIdx.x;
    float* base = out + (size_t)bt * (N_NODES * FDIM) + tid;

    float v[N_NODES];
#pragma unroll
    for (int nn = 0; nn < N_NODES; ++nn) v[nn] = base[nn * FDIM];

#pragma unroll 4
    for (int m = 0; m < N_NODES; ++m) {
        float s = 0.f;
#pragma unroll
        for (int nn = 0; nn < N_NODES; ++nn)
            s = fmaf(gs[m * N_NODES + nn], v[nn], s);
        base[m * FDIM] = s;
    }
}

extern "C" void kernel_launch(void* const* d_in, const int* in_sizes, int n_in,
                              void* d_out, int out_size, void* d_ws, size_t ws_size,
                              hipStream_t stream) {
    const float* input  = (const float*)d_in[0];
    const float* g      = (const float*)d_in[1];
    const int*   ntype  = (const int*)d_in[2];
    const float* weight = (const float*)d_in[3];
    const float* bias   = (const float*)d_in[4];
    float* out = (float*)d_out;
    __bf16* wp = (__bf16*)d_ws;   // needs 1 MB

    const int BT = in_sizes[0] / (N_NODES * FDIM);   // 4096

    // k0: 8*256*256 = 524288 elements
    k0_convert_w<<<N_TYPES * FDIM * FDIM / 256, 256, 0, stream>>>(weight, wp);

    dim3 g1(BT / BT_TILE, N_NODES);
    k1_node_gemm<<<g1, 256, 0, stream>>>(input, wp, bias, ntype, out);

    k2_graph_agg<<<BT, 256, 0, stream>>>(out, g);
}